// Round 17
// baseline (139.959 us; speedup 1.0000x reference)
//
#include <hip/hip_runtime.h>
#include <hip/hip_bf16.h>

#define T_TOK 2048
#define H_DIM 1024
#define I_DIM 768
#define NEXP  8
#define XSTR  1056   // padded x row stride (shorts)
#define WSTR  1056   // padded gate/up row stride (shorts)
#define LSTR  2560   // list entries per expert

typedef short bf16x8  __attribute__((ext_vector_type(8)));
typedef short short4v __attribute__((ext_vector_type(4)));
typedef float f32x4   __attribute__((ext_vector_type(4)));

__device__ __forceinline__ short f2bf(float f) {
  __bf16 b = (__bf16)f;
  return __builtin_bit_cast(short, b);
}
__device__ __forceinline__ void gload16(const void* g, void* l) {
  __builtin_amdgcn_global_load_lds(
      (const __attribute__((address_space(1))) void*)g,
      (__attribute__((address_space(3))) void*)l, 16, 0, 0);
}
__device__ __forceinline__ void ntst(unsigned short* p, short4v v) {
  __builtin_nontemporal_store(v, (short4v*)p);
}
__device__ __forceinline__ void ntstf(float* p, f32x4 v) {
  __builtin_nontemporal_store(v, (f32x4*)p);
}
__device__ __forceinline__ int padcnt(int c) { return (c + 127) & ~127; }
__device__ __forceinline__ int ebase(const int* __restrict__ cnts, int e) {
  int b = 0;
#pragma unroll
  for (int i = 0; i < NEXP; ++i)
    if (i < e) b += padcnt(cnts[i]);
  return b;
}

// ws layout (bytes): 0: counts[8] | 256: lists[8*2560]
// 131072: x_bf [2049][1056] (row 2048 = zeros)
// 4458560: gate_bf [6144][1056] | 17434688: up_bf [6144][1056]
// 30410816: down_bf [8192][768] | 42993728: h [6400][768]

// ---- kernel A: routing compaction; list tail -> token 2048 (zero row)
__global__ __launch_bounds__(512) void compact_k(const float* __restrict__ routw,
                                                 int* __restrict__ wsI) {
  __shared__ int sc[8];
  int e = blockIdx.x, tid = threadIdx.x, lane = tid & 63, w = tid >> 6;
  unsigned long long mk[4];
  int cnt = 0;
#pragma unroll
  for (int c = 0; c < 4; ++c) {
    int tk = w * 256 + c * 64 + lane;
    float v = routw[(size_t)tk * NEXP + e];
    mk[c] = __ballot(v > 0.f);
    cnt += __popcll(mk[c]);
  }
  if (lane == 0) sc[w] = cnt;
  __syncthreads();
  int run = 0, tot = 0;
#pragma unroll
  for (int j = 0; j < 8; ++j) {
    if (j < w) run += sc[j];
    tot += sc[j];
  }
#pragma unroll
  for (int c = 0; c < 4; ++c) {
    int tk = w * 256 + c * 64 + lane;
    if ((mk[c] >> lane) & 1ull) {
      int pos = __popcll(mk[c] & ((1ull << lane) - 1));
      wsI[64 + e * LSTR + run + pos] = tk;
    }
    run += __popcll(mk[c]);
  }
  if (w == 7 && lane == 0) wsI[e] = tot;
  for (int r = tot + tid; r < LSTR; r += 512) wsI[64 + e * LSTR + r] = T_TOK;
}

// ---- kernel B: conversions + zerofill, non-temporal stores.
// [0,520): x rows | [520,2056): gate | [2056,3592): up | [3592,5128): down | [5128,5640): zero out
__global__ __launch_bounds__(256) void pre_k(const float* __restrict__ x,
                                             const float* __restrict__ gw,
                                             const float* __restrict__ uw,
                                             const float* __restrict__ dw,
                                             unsigned short* __restrict__ x_bf,
                                             unsigned short* __restrict__ gbf,
                                             unsigned short* __restrict__ ubf,
                                             unsigned short* __restrict__ dbf,
                                             float* __restrict__ out) {
  int bid = blockIdx.x, tid = threadIdx.x;
  int col = (tid & 63) * 16;
  if (bid < 520) {
    int r = bid * 4 + (tid >> 6);
    if (r > 2048) return;
    unsigned short* dst = x_bf + (size_t)r * XSTR + col;
    if (r < 2048) {
      const float* sr = x + (size_t)r * H_DIM + col;
#pragma unroll
      for (int j = 0; j < 4; ++j) {
        float4 v = *(const float4*)(sr + j * 4);
        short4v b = {f2bf(v.x), f2bf(v.y), f2bf(v.z), f2bf(v.w)};
        ntst(dst + j * 4, b);
      }
    } else {
      short4v z = {0, 0, 0, 0};
#pragma unroll
      for (int j = 0; j < 4; ++j) ntst(dst + j * 4, z);
    }
  } else if (bid < 3592) {
    int a = (bid < 2056) ? 0 : 1;
    int r = (bid - (a ? 2056 : 520)) * 4 + (tid >> 6);
    const float* s = (a ? uw : gw) + (size_t)r * H_DIM + col;
    unsigned short* dst = (a ? ubf : gbf) + (size_t)r * WSTR + col;
#pragma unroll
    for (int j = 0; j < 4; ++j) {
      float4 v = *(const float4*)(s + j * 4);
      short4v b = {f2bf(v.x), f2bf(v.y), f2bf(v.z), f2bf(v.w)};
      ntst(dst + j * 4, b);
    }
  } else if (bid < 5128) {
    size_t off = ((size_t)(bid - 3592) * 256 + tid) * 16;
    const float* s = dw + off;
    unsigned short* o = dbf + off;
#pragma unroll
    for (int j = 0; j < 4; ++j) {
      float4 v = *(const float4*)(s + j * 4);
      short4v b = {f2bf(v.x), f2bf(v.y), f2bf(v.z), f2bf(v.w)};
      ntst(o + j * 4, b);
    }
  } else {
    size_t off = ((size_t)(bid - 5128) * 256 + tid) * 16;
    f32x4 z = {0.f, 0.f, 0.f, 0.f};
#pragma unroll
    for (int j = 0; j < 4; ++j) ntstf(out + off + j * 4, z);
  }
}

// ======== 8-phase 256^2 template (T3+T4), plain HIP port ========
// Tile 256M x 256N, BK=64, 512 thr / 8 waves (2M x 4N), wave tile 128x64.
// K-tile = 4 half-tiles {A0,A1,B0,B1} of 16KB; each phase stages ONE half
// (2 gload16/thread) of K-tile kt+1 and computes ONE C-quadrant of kt.
// vmcnt(2) only at phase 0 (counted, never 0 mid-loop); 2 barriers/phase.
// LDS 2 x 64KB dbuf. XOR-8 swizzle on source cols (linear gload_lds dest).

// ---- kernel C: gemm1: h = silu(X Wg^T) * (X Wu^T).
// B-tile rows = G[g0..g0+127] ++ U[g0..g0+127]; waves wn 0,1 = G cols, wn 2,3 = U.
// Epilogue: U-waves export via LDS, G-waves fuse SiLU and write h.
// grid = 8e * 8mt * 6nt = 384.
__global__ __launch_bounds__(512, 2) void gemm1_k(
    const unsigned short* __restrict__ x_bf, const unsigned short* __restrict__ gbf,
    const unsigned short* __restrict__ ubf, const int* __restrict__ wsI,
    unsigned short* __restrict__ h) {
  int e = blockIdx.x & 7, rr = blockIdx.x >> 3;
  int mt = rr & 7, nt = rr >> 3;          // mt 0..7, nt 0..5
  int cnt = wsI[e];
  int pad = padcnt(cnt);
  int m0 = mt * 256;
  if (m0 >= pad) return;
  int base = ebase(wsI, e);
  int g0 = nt * 128;

  __shared__ unsigned short ls[2][32768]; // per buf: A[256][64]@0, B[256][64]@16384

  int tid = threadIdx.x, lane = tid & 63, w = tid >> 6;
  int wm = w >> 2, wn = w & 3;
  int fr = lane & 15, fg = lane >> 4;
  int sr = lane >> 3, sg = (lane & 7) ^ sr;   // stage: row-in-chunk, swizzled src col

  const unsigned short* sA[2][2];
  const unsigned short* sB[2][2];
  int dA[2][2], dB[2][2];
#pragma unroll
  for (int hf = 0; hf < 2; ++hf)
#pragma unroll
    for (int ck = 0; ck < 2; ++ck) {
      int crow = 128 * hf + 16 * w + 8 * ck;          // chunk base row (wave-uniform)
      int tok = wsI[64 + e * LSTR + m0 + crow + sr];  // per-lane token gather
      sA[hf][ck] = x_bf + (size_t)tok * XSTR + sg * 8;
      dA[hf][ck] = crow * 64;
      const unsigned short* wsrc = hf ? ubf : gbf;
      sB[hf][ck] = wsrc + (size_t)(e * I_DIM + g0 + 16 * w + 8 * ck + sr) * WSTR + sg * 8;
      dB[hf][ck] = 16384 + crow * 64;
    }

  int roA[2][8], roB[2][4];
#pragma unroll
  for (int kk = 0; kk < 2; ++kk) {
#pragma unroll
    for (int m = 0; m < 8; ++m) {
      int R = wm * 128 + m * 16 + fr;
      roA[kk][m] = R * 64 + (((kk * 4 + fg) ^ (R & 7)) << 3);
    }
#pragma unroll
    for (int n = 0; n < 4; ++n) {
      int R = ((wn & 2) ? 128 : 0) + (wn & 1) * 64 + n * 16 + fr;
      roB[kk][n] = 16384 + R * 64 + (((kk * 4 + fg) ^ (R & 7)) << 3);
    }
  }

  f32x4 acc[8][4] = {};

#define STG1(b, kt, p)                                                 \
  do {                                                                 \
    if ((p) < 2) {                                                     \
      gload16(sA[(p)][0] + (kt) * 64, &ls[b][dA[(p)][0]]);             \
      gload16(sA[(p)][1] + (kt) * 64, &ls[b][dA[(p)][1]]);             \
    } else {                                                           \
      gload16(sB[(p)-2][0] + (kt) * 64, &ls[b][dB[(p)-2][0]]);         \
      gload16(sB[(p)-2][1] + (kt) * 64, &ls[b][dB[(p)-2][1]]);         \
    }                                                                  \
  } while (0)

  STG1(0, 0, 0); STG1(0, 0, 1); STG1(0, 0, 2); STG1(0, 0, 3);

  for (int kt = 0; kt < 16; ++kt) {
    int c = kt & 1;
    const unsigned short* lb = ls[c];
#pragma unroll
    for (int p = 0; p < 4; ++p) {
      int mh = p >> 1, nh = p & 1;
      bf16x8 af[4][2], bv[2][2];
      if (p == 0) {
        if (kt + 1 < 16) {
          STG1(c ^ 1, kt + 1, 0);
          asm volatile("s_waitcnt vmcnt(2)" ::: "memory");  // kt fully landed; 2 in flight
        } else {
          asm volatile("s_waitcnt vmcnt(0)" ::: "memory");  // tail drain
        }
        __builtin_amdgcn_s_barrier();
#pragma unroll
        for (int m = 0; m < 4; ++m)
#pragma unroll
          for (int kk = 0; kk < 2; ++kk)
            af[m][kk] = *(const bf16x8*)&lb[roA[kk][4 * mh + m]];
#pragma unroll
        for (int n = 0; n < 2; ++n)
#pragma unroll
          for (int kk = 0; kk < 2; ++kk)
            bv[n][kk] = *(const bf16x8*)&lb[roB[kk][2 * nh + n]];
      } else {
#pragma unroll
        for (int m = 0; m < 4; ++m)
#pragma unroll
          for (int kk = 0; kk < 2; ++kk)
            af[m][kk] = *(const bf16x8*)&lb[roA[kk][4 * mh + m]];
#pragma unroll
        for (int n = 0; n < 2; ++n)
#pragma unroll
          for (int kk = 0; kk < 2; ++kk)
            bv[n][kk] = *(const bf16x8*)&lb[roB[kk][2 * nh + n]];
        if (kt + 1 < 16) STG1(c ^ 1, kt + 1, p);
        __builtin_amdgcn_s_barrier();
      }
      asm volatile("s_waitcnt lgkmcnt(0)" ::: "memory");
      __builtin_amdgcn_sched_barrier(0);
      __builtin_amdgcn_s_setprio(1);
#pragma unroll
      for (int m = 0; m < 4; ++m)
#pragma unroll
        for (int n = 0; n < 2; ++n)
#pragma unroll
          for (int kk = 0; kk < 2; ++kk)
            acc[4 * mh + m][2 * nh + n] = __builtin_amdgcn_mfma_f32_16x16x32_bf16(
                af[m][kk], bv[n][kk], acc[4 * mh + m][2 * nh + n], 0, 0, 0);
      __builtin_amdgcn_s_setprio(0);
      __builtin_amdgcn_s_barrier();
    }
  }
#undef STG1

  // ---- epilogue: SiLU pairing via LDS exchange (staging LDS reused)
  float* uex = (float*)&ls[0][0];   // 4 quadrants x 128 x 64 f32 = 128KB
  if (wn >= 2) {
    int q = wm * 2 + (wn - 2);
#pragma unroll
    for (int m = 0; m < 8; ++m)
#pragma unroll
      for (int n = 0; n < 4; ++n)
#pragma unroll
        for (int j = 0; j < 4; ++j) {
          int row = m * 16 + fg * 4 + j;
          int col = (n * 16 + fr) ^ ((row & 3) << 4);   // bank-spread swizzle
          uex[q * 8192 + row * 64 + col] = acc[m][n][j];
        }
  }
  __syncthreads();
  if (wn < 2) {
    int q = wm * 2 + wn;
#pragma unroll
    for (int m = 0; m < 8; ++m)
#pragma unroll
      for (int j = 0; j < 4; ++j) {
        int row = m * 16 + fg * 4 + j;                  // C/D: col=lane&15, row=(lane>>4)*4+reg
        int grow = m0 + wm * 128 + row;
        if (grow < cnt) {
          size_t hb = (size_t)(base + grow) * I_DIM + g0 + wn * 64;
#pragma unroll
          for (int n = 0; n < 4; ++n) {
            float g = acc[m][n][j];
            int col = (n * 16 + fr) ^ ((row & 3) << 4);
            float u = uex[q * 8192 + row * 64 + col];
            h[hb + n * 16 + fr] = (unsigned short)f2bf(g * u / (1.f + __expf(-g)));
          }
        }
      }
  }
}

// ---- kernel D: gemm2: out[t] += rw * (h_e down^T). Same 8-phase template.
// Tile 256M x 256N, K=768 (12 K-tiles). grid = 8e * 8mt * 4nt = 256.
__global__ __launch_bounds__(512, 2) void gemm2_k(
    const unsigned short* __restrict__ h, const unsigned short* __restrict__ dbf,
    const int* __restrict__ wsI, const float* __restrict__ routw,
    float* __restrict__ out) {
  int e = blockIdx.x & 7, rr = blockIdx.x >> 3;
  int mt = rr & 7, nt = rr >> 3;          // mt 0..7, nt 0..3
  int cnt = wsI[e];
  int pad = padcnt(cnt);
  int m0 = mt * 256;
  if (m0 >= pad) return;
  int base = ebase(wsI, e);
  int n0 = nt * 256;

  __shared__ unsigned short ls[2][32768];

  int tid = threadIdx.x, lane = tid & 63, w = tid >> 6;
  int wm = w >> 2, wn = w & 3;
  int fr = lane & 15, fg = lane >> 4;
  int sr = lane >> 3, sg = (lane & 7) ^ sr;

  const unsigned short* sA[2][2];
  const unsigned short* sB[2][2];
  int dA[2][2], dB[2][2];
#pragma unroll
  for (int hf = 0; hf < 2; ++hf)
#pragma unroll
    for (int ck = 0; ck < 2; ++ck) {
      int crow = 128 * hf + 16 * w + 8 * ck;
      sA[hf][ck] = h + (size_t)(base + m0 + crow + sr) * I_DIM + sg * 8;
      dA[hf][ck] = crow * 64;
      sB[hf][ck] = dbf + (size_t)(e * H_DIM + n0 + crow + sr) * I_DIM + sg * 8;
      dB[hf][ck] = 16384 + crow * 64;
    }

  int roA[2][8], roB[2][4];
#pragma unroll
  for (int kk = 0; kk < 2; ++kk) {
#pragma unroll
    for (int m = 0; m < 8; ++m) {
      int R = wm * 128 + m * 16 + fr;
      roA[kk][m] = R * 64 + (((kk * 4 + fg) ^ (R & 7)) << 3);
    }
#pragma unroll
    for (int n = 0; n < 4; ++n) {
      int R = wn * 64 + n * 16 + fr;
      roB[kk][n] = 16384 + R * 64 + (((kk * 4 + fg) ^ (R & 7)) << 3);
    }
  }

  f32x4 acc[8][4] = {};

#define STG2(b, kt, p)                                                 \
  do {                                                                 \
    if ((p) < 2) {                                                     \
      gload16(sA[(p)][0] + (kt) * 64, &ls[b][dA[(p)][0]]);             \
      gload16(sA[(p)][1] + (kt) * 64, &ls[b][dA[(p)][1]]);             \
    } else {                                                           \
      gload16(sB[(p)-2][0] + (kt) * 64, &ls[b][dB[(p)-2][0]]);         \
      gload16(sB[(p)-2][1] + (kt) * 64, &ls[b][dB[(p)-2][1]]);         \
    }                                                                  \
  } while (0)

  STG2(0, 0, 0); STG2(0, 0, 1); STG2(0, 0, 2); STG2(0, 0, 3);

  for (int kt = 0; kt < 12; ++kt) {
    int c = kt & 1;
    const unsigned short* lb = ls[c];
#pragma unroll
    for (int p = 0; p < 4; ++p) {
      int mh = p >> 1, nh = p & 1;
      bf16x8 af[4][2], bv[2][2];
      if (p == 0) {
        if (kt + 1 < 12) {
          STG2(c ^ 1, kt + 1, 0);
          asm volatile("s_waitcnt vmcnt(2)" ::: "memory");
        } else {
          asm volatile("s_waitcnt vmcnt(0)" ::: "memory");
        }
        __builtin_amdgcn_s_barrier();
#pragma unroll
        for (int m = 0; m < 4; ++m)
#pragma unroll
          for (int kk = 0; kk < 2; ++kk)
            af[m][kk] = *(const bf16x8*)&lb[roA[kk][4 * mh + m]];
#pragma unroll
        for (int n = 0; n < 2; ++n)
#pragma unroll
          for (int kk = 0; kk < 2; ++kk)
            bv[n][kk] = *(const bf16x8*)&lb[roB[kk][2 * nh + n]];
      } else {
#pragma unroll
        for (int m = 0; m < 4; ++m)
#pragma unroll
          for (int kk = 0; kk < 2; ++kk)
            af[m][kk] = *(const bf16x8*)&lb[roA[kk][4 * mh + m]];
#pragma unroll
        for (int n = 0; n < 2; ++n)
#pragma unroll
          for (int kk = 0; kk < 2; ++kk)
            bv[n][kk] = *(const bf16x8*)&lb[roB[kk][2 * nh + n]];
        if (kt + 1 < 12) STG2(c ^ 1, kt + 1, p);
        __builtin_amdgcn_s_barrier();
      }
      asm volatile("s_waitcnt lgkmcnt(0)" ::: "memory");
      __builtin_amdgcn_sched_barrier(0);
      __builtin_amdgcn_s_setprio(1);
#pragma unroll
      for (int m = 0; m < 4; ++m)
#pragma unroll
        for (int n = 0; n < 2; ++n)
#pragma unroll
          for (int kk = 0; kk < 2; ++kk)
            acc[4 * mh + m][2 * nh + n] = __builtin_amdgcn_mfma_f32_16x16x32_bf16(
                af[m][kk], bv[n][kk], acc[4 * mh + m][2 * nh + n], 0, 0, 0);
      __builtin_amdgcn_s_setprio(0);
      __builtin_amdgcn_s_barrier();
    }
  }
#undef STG2

#pragma unroll
  for (int m = 0; m < 8; ++m)
#pragma unroll
    for (int j = 0; j < 4; ++j) {
      int row = m * 16 + fg * 4 + j;
      int grow = m0 + wm * 128 + row;
      if (grow < cnt) {
        int tk = wsI[64 + e * LSTR + grow];
        float rw = routw[(size_t)tk * NEXP + e];
        float* orow = out + (size_t)tk * H_DIM + n0 + wn * 64;
#pragma unroll
        for (int n = 0; n < 4; ++n)
          atomicAdd(orow + n * 16 + fr, acc[m][n][j] * rw);
      }
    }
}

extern "C" void kernel_launch(void* const* d_in, const int* in_sizes, int n_in,
                              void* d_out, int out_size, void* d_ws, size_t ws_size,
                              hipStream_t stream) {
  const float* x      = (const float*)d_in[0];
  const float* gate_w = (const float*)d_in[1];
  const float* up_w   = (const float*)d_in[2];
  const float* down_w = (const float*)d_in[3];
  const float* routw  = (const float*)d_in[4];
  float* out = (float*)d_out;
  int* wsI = (int*)d_ws;

  unsigned short* x_bf = (unsigned short*)((char*)d_ws + 131072);
  unsigned short* gbf  = (unsigned short*)((char*)d_ws + 4458560);
  unsigned short* ubf  = (unsigned short*)((char*)d_ws + 17434688);
  unsigned short* dbf  = (unsigned short*)((char*)d_ws + 30410816);
  unsigned short* h    = (unsigned short*)((char*)d_ws + 42993728);

  compact_k<<<8, 512, 0, stream>>>(routw, wsI);
  pre_k<<<5640, 256, 0, stream>>>(x, gate_w, up_w, down_w, x_bf, gbf, ubf, dbf, out);
  gemm1_k<<<384, 512, 0, stream>>>(x_bf, gbf, ubf, wsI, h);
  gemm2_k<<<256, 512, 0, stream>>>(h, dbf, wsI, routw, out);
}